// Round 2
// baseline (4032.235 us; speedup 1.0000x reference)
//
#include <hip/hip_runtime.h>
#include <complex>
#include <cmath>

// ---------------------------------------------------------------------------
// MarioNette layer (e3nn-style): node linears -> edge tensor-product messages
// with radial MLP weights -> segment sum -> squared tensor products -> output
// linears + soft-norm + skip.  MUL=64, lmax=2, 20000 nodes, 160000 edges.
//
// Internal layout: component-major (i-major) per node/edge so lane=u gathers
// and atomics are 64-lane coalesced 256B segments. Output converted back to
// u-major in the final kernel.
// ---------------------------------------------------------------------------

constexpr int NN = 20000;
constexpr int NE = 160000;

struct CGTab { float v[363]; };
// path order (== PATHS order): (0,0,0)(0,1,1)(0,2,2)(1,0,1)(1,1,0)(1,1,2)
//                              (1,2,1)(2,0,2)(2,1,1)(2,2,0)(2,2,2)
// sizes: 1,9,25,9,9,45,45,25,45,25,125 ; offsets:
// 0,1,10,35,44,53,98,143,168,213,238  (total 363)

// ---------------- host-side CG construction (exact port of reference) ------
static double hfact(int n){ double r=1.0; for(int i=2;i<=n;i++) r*=(double)i; return r; }
static double hcleb(int j1,int m1,int j2,int m2,int j3,int m3){
  if(m1+m2!=m3) return 0.0;
  double pref = std::sqrt((2.0*j3+1.0)*hfact(j3+j1-j2)*hfact(j3-j1+j2)*hfact(j1+j2-j3)/hfact(j1+j2+j3+1));
  pref *= std::sqrt(hfact(j3+m3)*hfact(j3-m3)*hfact(j1-m1)*hfact(j1+m1)*hfact(j2-m2)*hfact(j2+m2));
  double s=0.0;
  for(int k=0;k<=j1+j2-j3;k++){
    int d0=k,d1=j1+j2-j3-k,d2=j1-m1-k,d3=j2+m2-k,d4=j3-j2+m1+k,d5=j3-j1-m2+k;
    if(d0<0||d1<0||d2<0||d3<0||d4<0||d5<0) continue;
    double den=hfact(d0)*hfact(d1)*hfact(d2)*hfact(d3)*hfact(d4)*hfact(d5);
    s += ((k&1)?-1.0:1.0)/den;
  }
  return pref*s;
}
typedef std::complex<double> cdbl;
static void hbuildU(int l, cdbl U[5][5]){
  for(int a=0;a<5;a++)for(int b=0;b<5;b++) U[a][b]=cdbl(0.0,0.0);
  U[l][l]=cdbl(1.0,0.0);
  const double r2=std::sqrt(2.0);
  for(int m=1;m<=l;m++){
    double sgn=(m&1)?-1.0:1.0;
    U[l+m][l+m]=cdbl(sgn/r2,0.0);
    U[l+m][l-m]=cdbl(1.0/r2,0.0);
    U[l-m][l-m]=cdbl(0.0,1.0/r2);
    U[l-m][l+m]=cdbl(0.0,-sgn/r2);
  }
}
static CGTab build_cg(){
  CGTab T{};
  const int L1[11]={0,0,0,1,1,1,1,2,2,2,2};
  const int L2[11]={0,1,2,0,1,1,2,0,1,2,2};
  const int L3[11]={0,1,2,1,0,2,1,2,1,0,2};
  int off=0;
  for(int p=0;p<11;p++){
    int l1=L1[p],l2=L2[p],l3=L3[p];
    int d1=2*l1+1,d2=2*l2+1,d3=2*l3+1;
    cdbl U1[5][5],U2[5][5],U3[5][5];
    hbuildU(l1,U1); hbuildU(l2,U2); hbuildU(l3,U3);
    double Rr[125],Ri[125]; double nr=0.0,ni=0.0;
    for(int a=0;a<d1;a++)for(int b=0;b<d2;b++)for(int c=0;c<d3;c++){
      cdbl s(0.0,0.0);
      for(int i=0;i<d1;i++)for(int j=0;j<d2;j++){
        int k=(i-l1)+(j-l2)+l3;          // m3 = m1+m2 selection rule
        if(k<0||k>=d3) continue;
        double cc=hcleb(l1,i-l1,l2,j-l2,l3,k-l3);
        if(cc==0.0) continue;
        s += U1[a][i]*U2[b][j]*std::conj(U3[c][k])*cc;
      }
      int idx=(a*d2+b)*d3+c;
      Rr[idx]=s.real(); Ri[idx]=s.imag();
      nr+=s.real()*s.real(); ni+=s.imag()*s.imag();
    }
    bool useR=(nr>=ni);
    double nm=std::sqrt(useR?nr:ni);
    int sz=d1*d2*d3;
    for(int t=0;t<sz;t++) T.v[off+t]=(float)((useR?Rr[t]:Ri[t])/nm);
    off+=sz;
  }
  return T;
}
static const CGTab g_cg = build_cg();

// ---------------- device helpers -------------------------------------------
__device__ __forceinline__ float gelu_f(float x){
  // jax.nn.gelu default (approximate=True, tanh form)
  float t = tanhf(0.7978845608028654f*(x + 0.044715f*x*x*x));
  return 0.5f*x*(1.0f+t);
}

// ---------------- K1: up = nf @ W_up / 8  (stored component-major) ----------
__global__ __launch_bounds__(256) void node_up_kernel(
    const float* __restrict__ nf, const float* __restrict__ Wup,
    float* __restrict__ up)
{
  __shared__ alignas(16) float NF[4][576];
  const int tid=threadIdx.x, wid=tid>>6, lane=tid&63;
  const int node=blockIdx.x*4+wid;
  float* F=NF[wid];
  const float* nr=nf+(size_t)node*576;
  #pragma unroll
  for(int t=0;t<9;t++) F[lane+t*64]=nr[lane+t*64];
  __syncthreads();
  float* ur=up+(size_t)node*576;
  { // l=0
    float a=0.f;
    for(int u4=0;u4<16;u4++){
      const float* wb=Wup+(u4*4)*64+lane;
      float w0=wb[0],w1=wb[64],w2=wb[128],w3=wb[192];
      const float4 v=*(const float4*)&F[u4*4];
      a+=v.x*w0+v.y*w1+v.z*w2+v.w*w3;
    }
    ur[lane]=a*0.125f;
  }
  { // l=1 : input u-major F[64+u*3+i]
    float a0=0.f,a1=0.f,a2=0.f;
    for(int u4=0;u4<16;u4++){
      const float* wb=Wup+4096+(u4*4)*64+lane;
      float w0=wb[0],w1=wb[64],w2=wb[128],w3=wb[192];
      const float4 A0=*(const float4*)&F[64+u4*12];
      const float4 A1=*(const float4*)&F[64+u4*12+4];
      const float4 A2=*(const float4*)&F[64+u4*12+8];
      a0 += A0.x*w0 + A0.w*w1 + A1.z*w2 + A2.y*w3;
      a1 += A0.y*w0 + A1.x*w1 + A1.w*w2 + A2.z*w3;
      a2 += A0.z*w0 + A1.y*w1 + A2.x*w2 + A2.w*w3;
    }
    ur[64+lane]=a0*0.125f; ur[128+lane]=a1*0.125f; ur[192+lane]=a2*0.125f;
  }
  { // l=2 : input u-major F[256+u*5+i]
    float a0=0.f,a1=0.f,a2=0.f,a3=0.f,a4=0.f;
    for(int u4=0;u4<16;u4++){
      const float* wb=Wup+8192+(u4*4)*64+lane;
      float w0=wb[0],w1=wb[64],w2=wb[128],w3=wb[192];
      const float4 B0=*(const float4*)&F[256+u4*20];
      const float4 B1=*(const float4*)&F[256+u4*20+4];
      const float4 B2=*(const float4*)&F[256+u4*20+8];
      const float4 B3=*(const float4*)&F[256+u4*20+12];
      const float4 B4=*(const float4*)&F[256+u4*20+16];
      a0 += B0.x*w0 + B1.y*w1 + B2.z*w2 + B3.w*w3;
      a1 += B0.y*w0 + B1.z*w1 + B2.w*w2 + B4.x*w3;
      a2 += B0.z*w0 + B1.w*w1 + B3.x*w2 + B4.y*w3;
      a3 += B0.w*w0 + B2.x*w1 + B3.y*w2 + B4.z*w3;
      a4 += B1.x*w0 + B2.y*w1 + B3.z*w2 + B4.w*w3;
    }
    ur[256+lane]=a0*0.125f; ur[320+lane]=a1*0.125f; ur[384+lane]=a2*0.125f;
    ur[448+lane]=a3*0.125f; ur[512+lane]=a4*0.125f;
  }
}

// ---------------- K2: per-edge radial MLP + tensor-product + scatter --------
// 1 wave = 8 edges; block = 4 waves = 32 edges.
__global__ __launch_bounds__(256) void edge_kernel(
    const float* __restrict__ vectors, const int* __restrict__ senders,
    const int* __restrict__ receivers, const float* __restrict__ M1,
    const float* __restrict__ M2, const float* __restrict__ M3,
    const float* __restrict__ up, float* __restrict__ agg, CGTab cg)
{
  __shared__ alignas(16) float RL[4][64];
  __shared__ alignas(16) float HL[4][512];
  __shared__ alignas(16) float HL2[4][512];
  const int tid=threadIdx.x, wid=tid>>6, lane=tid&63;
  const int ebase=(blockIdx.x*4+wid)*8;

  // radial basis: lane handles edge (lane>>3), basis (lane&7)
  {
    int el = ebase + (lane>>3);
    float vx=vectors[3*el], vy=vectors[3*el+1], vz=vectors[3*el+2];
    float xx=sqrtf(vx*vx+vy*vy+vz*vz);
    float safe=(xx==0.0f)?1.0f:xx;
    float x2=xx*xx;
    float env=(xx<1.0f)? expf(2.0f*x2/fminf(x2-1.0f,-1e-6f)) : 0.0f;
    float nb=(float)((lane&7)+1);
    RL[wid][lane] = 1.4142135623730951f*sinf(3.14159265358979f*nb*xx)/safe*env;
  }
  __syncthreads();
  // h1 = gelu(r @ M1 / sqrt(8))
  {
    float m1v[8];
    #pragma unroll
    for(int b=0;b<8;b++) m1v[b]=M1[b*64+lane];
    #pragma unroll
    for(int e=0;e<8;e++){
      const float4 ra=*(const float4*)&RL[wid][e*8];
      const float4 rb=*(const float4*)&RL[wid][e*8+4];
      float acc = ra.x*m1v[0]+ra.y*m1v[1]+ra.z*m1v[2]+ra.w*m1v[3]
                + rb.x*m1v[4]+rb.y*m1v[5]+rb.z*m1v[6]+rb.w*m1v[7];
      HL[wid][e*64+lane]=gelu_f(acc*0.3535533905932738f);
    }
  }
  __syncthreads();
  // h2 = gelu(h1 @ M2 / 8)
  {
    float h2[8]={0,0,0,0,0,0,0,0};
    for(int k4=0;k4<16;k4++){
      const float* mb=M2+(k4*4)*64+lane;
      float m2a=mb[0],m2b=mb[64],m2c=mb[128],m2d=mb[192];
      #pragma unroll
      for(int e=0;e<8;e++){
        const float4 h=*(const float4*)&HL[wid][e*64+k4*4];
        h2[e] += h.x*m2a+h.y*m2b+h.z*m2c+h.w*m2d;
      }
    }
    #pragma unroll
    for(int e=0;e<8;e++) HL2[wid][e*64+lane]=gelu_f(h2[e]*0.125f);
  }
  __syncthreads();
  // w[e][p] = (h2 @ M3)[p*64+lane]   (scale 1/8 applied later)
  float w[8][11];
  #pragma unroll
  for(int e=0;e<8;e++){
    #pragma unroll
    for(int p=0;p<11;p++) w[e][p]=0.0f;
  }
  for(int k4=0;k4<16;k4++){
    float m3v[4][11];
    #pragma unroll
    for(int q=0;q<4;q++){
      #pragma unroll
      for(int p=0;p<11;p++) m3v[q][p]=M3[(size_t)(k4*4+q)*704+p*64+lane];
    }
    #pragma unroll
    for(int e=0;e<8;e++){
      const float4 h=*(const float4*)&HL2[wid][e*64+k4*4];
      #pragma unroll
      for(int p=0;p<11;p++)
        w[e][p] += h.x*m3v[0][p]+h.y*m3v[1][p]+h.z*m3v[2][p]+h.w*m3v[3][p];
    }
  }
  // per-edge tensor product + atomic scatter
  #pragma unroll
  for(int e=0;e<8;e++){
    const int eid=ebase+e;
    float evx=vectors[3*eid], evy=vectors[3*eid+1], evz=vectors[3*eid+2];
    float len=sqrtf(evx*evx+evy*evy+evz*evz);
    float il=1.0f/fmaxf(len,1e-9f);
    float dx=evx*il, dy=evy*il, dz=evz*il;
    float Y1[3]={1.7320508075688772f*dy, 1.7320508075688772f*dz, 1.7320508075688772f*dx};
    float Y2[5]={3.872983346207417f*dx*dy, 3.872983346207417f*dy*dz,
                 1.118033988749895f*(3.0f*dz*dz-1.0f),
                 3.872983346207417f*dx*dz, 1.9364916731037085f*(dx*dx-dy*dy)};
    int snd=senders[eid], rcv=receivers[eid];
    const float* urow=up+(size_t)snd*576;
    float mA=urow[lane];
    float mB[3], mC[5];
    #pragma unroll
    for(int i=0;i<3;i++) mB[i]=urow[64+i*64+lane];
    #pragma unroll
    for(int i=0;i<5;i++) mC[i]=urow[256+i*64+lane];
    const float wsc=(len==0.0f)?0.0f:0.125f;   // mix/8 and zero at len==0
    float we[11];
    #pragma unroll
    for(int p=0;p<11;p++) we[p]=w[e][p]*wsc;
    float o0=0.0f, o1[3]={0,0,0}, o2[5]={0,0,0,0,0};
    // (0,0,0)
    o0 += we[0]*mA*cg.v[0];
    // (0,1,1): diagonal (U unitarity)
    #pragma unroll
    for(int k=0;k<3;k++) o1[k]+= we[1]*mA*Y1[k]*cg.v[1+k*3+k];
    // (0,2,2): diagonal
    #pragma unroll
    for(int k=0;k<5;k++) o2[k]+= we[2]*mA*Y2[k]*cg.v[10+k*5+k];
    // (1,0,1): diagonal
    #pragma unroll
    for(int k=0;k<3;k++) o1[k]+= we[3]*mB[k]*cg.v[35+k*3+k];
    // (1,1,0)
    #pragma unroll
    for(int i=0;i<3;i++){
      float t=we[4]*mB[i];
      #pragma unroll
      for(int j=0;j<3;j++) o0 += t*Y1[j]*cg.v[44+i*3+j];
    }
    // (1,1,2)
    #pragma unroll
    for(int i=0;i<3;i++){
      float t=we[5]*mB[i];
      #pragma unroll
      for(int j=0;j<3;j++){
        float ty=t*Y1[j];
        #pragma unroll
        for(int k=0;k<5;k++) o2[k]+= ty*cg.v[53+(i*3+j)*5+k];
      }
    }
    // (1,2,1)
    #pragma unroll
    for(int i=0;i<3;i++){
      float t=we[6]*mB[i];
      #pragma unroll
      for(int j=0;j<5;j++){
        float ty=t*Y2[j];
        #pragma unroll
        for(int k=0;k<3;k++) o1[k]+= ty*cg.v[98+(i*5+j)*3+k];
      }
    }
    // (2,0,2): diagonal
    #pragma unroll
    for(int k=0;k<5;k++) o2[k]+= we[7]*mC[k]*cg.v[143+k*5+k];
    // (2,1,1)
    #pragma unroll
    for(int i=0;i<5;i++){
      float t=we[8]*mC[i];
      #pragma unroll
      for(int j=0;j<3;j++){
        float ty=t*Y1[j];
        #pragma unroll
        for(int k=0;k<3;k++) o1[k]+= ty*cg.v[168+(i*3+j)*3+k];
      }
    }
    // (2,2,0)
    #pragma unroll
    for(int i=0;i<5;i++){
      float t=we[9]*mC[i];
      #pragma unroll
      for(int j=0;j<5;j++) o0 += t*Y2[j]*cg.v[213+i*5+j];
    }
    // (2,2,2)
    #pragma unroll
    for(int i=0;i<5;i++){
      float t=we[10]*mC[i];
      #pragma unroll
      for(int j=0;j<5;j++){
        float ty=t*Y2[j];
        #pragma unroll
        for(int k=0;k<5;k++) o2[k]+= ty*cg.v[238+(i*5+j)*5+k];
      }
    }
    float* ar=agg+(size_t)rcv*576;
    const float sc=0.3535533905932738f;  // 1/sqrt(AVG_NEIGH)
    atomicAdd(ar+lane, o0*sc);
    #pragma unroll
    for(int i=0;i<3;i++) atomicAdd(ar+64+i*64+lane, o1[i]*sc);
    #pragma unroll
    for(int i=0;i<5;i++) atomicAdd(ar+256+i*64+lane, o2[i]*sc);
  }
}

// ---------------- K3: dn, squares, output linears, soft-norm, skip, merge ---
__global__ __launch_bounds__(256) void final_kernel(
    const float* __restrict__ agg, const float* __restrict__ nf,
    const int* __restrict__ specie, const float* __restrict__ Wskip,
    const float* __restrict__ Wdown, const float* __restrict__ Wout0,
    const float* __restrict__ Wout1, const float* __restrict__ Wout2,
    float* __restrict__ out, CGTab cg)
{
  __shared__ alignas(16) float AG[4][576];
  __shared__ alignas(16) float NF[4][576];
  __shared__ alignas(16) float C0[4][256];
  __shared__ alignas(16) float C1[4][576];
  __shared__ alignas(16) float C2[4][1280];
  const int tid=threadIdx.x, wid=tid>>6, lane=tid&63;
  const int node=blockIdx.x*4+wid;
  float* A=AG[wid]; float* F=NF[wid];
  {
    const float* ar=agg+(size_t)node*576;
    const float* nr=nf+(size_t)node*576;
    #pragma unroll
    for(int t=0;t<9;t++){ A[lane+t*64]=ar[lane+t*64]; F[lane+t*64]=nr[lane+t*64]; }
  }
  __syncthreads();
  const int sp=specie[node];
  const float* Ws=Wskip+(size_t)sp*12288;
  float sk0, sk1[3], sk2[5];
  { // skip l0
    float a=0.f;
    for(int u4=0;u4<16;u4++){
      const float* wb=Ws+(u4*4)*64+lane;
      float w0=wb[0],w1=wb[64],w2=wb[128],w3=wb[192];
      const float4 v=*(const float4*)&F[u4*4];
      a+=v.x*w0+v.y*w1+v.z*w2+v.w*w3;
    }
    sk0=a*0.125f;
  }
  { // skip l1 (F u-major)
    float a0=0.f,a1=0.f,a2=0.f;
    for(int u4=0;u4<16;u4++){
      const float* wb=Ws+4096+(u4*4)*64+lane;
      float w0=wb[0],w1=wb[64],w2=wb[128],w3=wb[192];
      const float4 A0=*(const float4*)&F[64+u4*12];
      const float4 A1=*(const float4*)&F[64+u4*12+4];
      const float4 A2=*(const float4*)&F[64+u4*12+8];
      a0 += A0.x*w0 + A0.w*w1 + A1.z*w2 + A2.y*w3;
      a1 += A0.y*w0 + A1.x*w1 + A1.w*w2 + A2.z*w3;
      a2 += A0.z*w0 + A1.y*w1 + A2.x*w2 + A2.w*w3;
    }
    sk1[0]=a0*0.125f; sk1[1]=a1*0.125f; sk1[2]=a2*0.125f;
  }
  { // skip l2
    float a0=0.f,a1=0.f,a2=0.f,a3=0.f,a4=0.f;
    for(int u4=0;u4<16;u4++){
      const float* wb=Ws+8192+(u4*4)*64+lane;
      float w0=wb[0],w1=wb[64],w2=wb[128],w3=wb[192];
      const float4 B0=*(const float4*)&F[256+u4*20];
      const float4 B1=*(const float4*)&F[256+u4*20+4];
      const float4 B2=*(const float4*)&F[256+u4*20+8];
      const float4 B3=*(const float4*)&F[256+u4*20+12];
      const float4 B4=*(const float4*)&F[256+u4*20+16];
      a0 += B0.x*w0 + B1.y*w1 + B2.z*w2 + B3.w*w3;
      a1 += B0.y*w0 + B1.z*w1 + B2.w*w2 + B4.x*w3;
      a2 += B0.z*w0 + B1.w*w1 + B3.x*w2 + B4.y*w3;
      a3 += B0.w*w0 + B2.x*w1 + B3.y*w2 + B4.z*w3;
      a4 += B1.x*w0 + B2.y*w1 + B3.z*w2 + B4.w*w3;
    }
    sk2[0]=a0*0.125f; sk2[1]=a1*0.125f; sk2[2]=a2*0.125f; sk2[3]=a3*0.125f; sk2[4]=a4*0.125f;
  }
  // dn = agg @ W_down / 8   (A is component-major)
  float dn0, dn1[3], dn2[5];
  {
    float a=0.f;
    for(int u4=0;u4<16;u4++){
      const float* wb=Wdown+(u4*4)*64+lane;
      float w0=wb[0],w1=wb[64],w2=wb[128],w3=wb[192];
      const float4 v=*(const float4*)&A[u4*4];
      a+=v.x*w0+v.y*w1+v.z*w2+v.w*w3;
    }
    dn0=gelu_f(a*0.125f);
  }
  {
    float a0=0.f,a1=0.f,a2=0.f;
    for(int u4=0;u4<16;u4++){
      const float* wb=Wdown+4096+(u4*4)*64+lane;
      float w0=wb[0],w1=wb[64],w2=wb[128],w3=wb[192];
      const float4 v0=*(const float4*)&A[64+u4*4];
      const float4 v1=*(const float4*)&A[128+u4*4];
      const float4 v2=*(const float4*)&A[192+u4*4];
      a0+=v0.x*w0+v0.y*w1+v0.z*w2+v0.w*w3;
      a1+=v1.x*w0+v1.y*w1+v1.z*w2+v1.w*w3;
      a2+=v2.x*w0+v2.y*w1+v2.z*w2+v2.w*w3;
    }
    dn1[0]=a0*0.125f; dn1[1]=a1*0.125f; dn1[2]=a2*0.125f;
  }
  {
    float a[5]={0,0,0,0,0};
    for(int u4=0;u4<16;u4++){
      const float* wb=Wdown+8192+(u4*4)*64+lane;
      float w0=wb[0],w1=wb[64],w2=wb[128],w3=wb[192];
      #pragma unroll
      for(int i=0;i<5;i++){
        const float4 v=*(const float4*)&A[256+i*64+u4*4];
        a[i]+=v.x*w0+v.y*w1+v.z*w2+v.w*w3;
      }
    }
    #pragma unroll
    for(int i=0;i<5;i++) dn2[i]=a[i]*0.125f;
  }
  // lane-local squared tensor products (u = lane)
  float sq000 = dn0*dn0*cg.v[0];
  float sq011[3], sq022[5];
  #pragma unroll
  for(int k=0;k<3;k++) sq011[k]=dn0*dn1[k]*cg.v[1+k*3+k];
  #pragma unroll
  for(int k=0;k<5;k++) sq022[k]=dn0*dn2[k]*cg.v[10+k*5+k];
  float sq110=0.f;
  #pragma unroll
  for(int i=0;i<3;i++){
    #pragma unroll
    for(int j=0;j<3;j++) sq110+=dn1[i]*dn1[j]*cg.v[44+i*3+j];
  }
  float sq112[5]={0,0,0,0,0};
  #pragma unroll
  for(int i=0;i<3;i++){
    #pragma unroll
    for(int j=0;j<3;j++){
      float t=dn1[i]*dn1[j];
      #pragma unroll
      for(int k=0;k<5;k++) sq112[k]+=t*cg.v[53+(i*3+j)*5+k];
    }
  }
  float sq121[3]={0,0,0};
  #pragma unroll
  for(int i=0;i<3;i++){
    #pragma unroll
    for(int j=0;j<5;j++){
      float t=dn1[i]*dn2[j];
      #pragma unroll
      for(int k=0;k<3;k++) sq121[k]+=t*cg.v[98+(i*5+j)*3+k];
    }
  }
  float sq220=0.f;
  #pragma unroll
  for(int i=0;i<5;i++){
    #pragma unroll
    for(int j=0;j<5;j++) sq220+=dn2[i]*dn2[j]*cg.v[213+i*5+j];
  }
  float sq222[5]={0,0,0,0,0};
  #pragma unroll
  for(int i=0;i<5;i++){
    #pragma unroll
    for(int j=0;j<5;j++){
      float t=dn2[i]*dn2[j];
      #pragma unroll
      for(int k=0;k<5;k++) sq222[k]+=t*cg.v[238+(i*5+j)*5+k];
    }
  }
  // cats into LDS (component-major)
  {
    float* CC=C0[wid];
    CC[lane]=dn0; CC[64+lane]=sq000; CC[128+lane]=sq110; CC[192+lane]=sq220;
  }
  {
    float* CC=C1[wid];
    #pragma unroll
    for(int i=0;i<3;i++){ CC[i*192+lane]=dn1[i]; CC[i*192+64+lane]=sq011[i]; CC[i*192+128+lane]=sq121[i]; }
  }
  {
    float* CC=C2[wid];
    #pragma unroll
    for(int i=0;i<5;i++){ CC[i*256+lane]=dn2[i]; CC[i*256+64+lane]=sq022[i]; CC[i*256+128+lane]=sq112[i]; CC[i*256+192+lane]=sq222[i]; }
  }
  __syncthreads();
  // output linears
  float o0=0.f;
  {
    const float* CC=C0[wid];
    for(int u4=0;u4<64;u4++){
      const float* wb=Wout0+(u4*4)*64+lane;
      float w0=wb[0],w1=wb[64],w2=wb[128],w3=wb[192];
      const float4 v=*(const float4*)&CC[u4*4];
      o0+=v.x*w0+v.y*w1+v.z*w2+v.w*w3;
    }
    o0*=0.0625f;
  }
  float o1[3]={0,0,0};
  {
    const float* CC=C1[wid];
    for(int u4=0;u4<48;u4++){
      const float* wb=Wout1+(u4*4)*64+lane;
      float w0=wb[0],w1=wb[64],w2=wb[128],w3=wb[192];
      #pragma unroll
      for(int i=0;i<3;i++){
        const float4 v=*(const float4*)&CC[i*192+u4*4];
        o1[i]+=v.x*w0+v.y*w1+v.z*w2+v.w*w3;
      }
    }
    #pragma unroll
    for(int i=0;i<3;i++) o1[i]*=0.07216878364870323f;
  }
  float o2[5]={0,0,0,0,0};
  {
    const float* CC=C2[wid];
    for(int u4=0;u4<64;u4++){
      const float* wb=Wout2+(u4*4)*64+lane;
      float w0=wb[0],w1=wb[64],w2=wb[128],w3=wb[192];
      #pragma unroll
      for(int i=0;i<5;i++){
        const float4 v=*(const float4*)&CC[i*256+u4*4];
        o2[i]+=v.x*w0+v.y*w1+v.z*w2+v.w*w3;
      }
    }
    #pragma unroll
    for(int i=0;i<5;i++) o2[i]*=0.0625f;
  }
  // soft norm factors
  float f0,f1,f2;
  { float n=fabsf(o0)*1e-5f;
    float s=(n>0.0f)?expf(-1.0f/n):0.0f; f0=1.0f/(1.0f+n*s); }
  { float n=sqrtf(o1[0]*o1[0]+o1[1]*o1[1]+o1[2]*o1[2])*1e-5f;
    float s=(n>0.0f)?expf(-1.0f/n):0.0f; f1=1.0f/(1.0f+n*s); }
  { float n=sqrtf(o2[0]*o2[0]+o2[1]*o2[1]+o2[2]*o2[2]+o2[3]*o2[3]+o2[4]*o2[4])*1e-5f;
    float s=(n>0.0f)?expf(-1.0f/n):0.0f; f2=1.0f/(1.0f+n*s); }
  __syncthreads();
  // merge (u-major output layout) via LDS, then coalesced store
  A[lane]=0.9f*sk0+0.45f*o0*f0;
  #pragma unroll
  for(int i=0;i<3;i++) A[64+lane*3+i]=0.9f*sk1[i]+0.45f*o1[i]*f1;
  #pragma unroll
  for(int i=0;i<5;i++) A[256+lane*5+i]=0.9f*sk2[i]+0.45f*o2[i]*f2;
  __syncthreads();
  float* orow=out+(size_t)node*576;
  #pragma unroll
  for(int t=0;t<9;t++) orow[lane+t*64]=A[lane+t*64];
}

// ---------------- launch ----------------------------------------------------
extern "C" void kernel_launch(void* const* d_in, const int* in_sizes, int n_in,
                              void* d_out, int out_size, void* d_ws, size_t ws_size,
                              hipStream_t stream) {
  (void)in_sizes; (void)n_in; (void)out_size; (void)ws_size;
  const float* vectors    =(const float*)d_in[0];
  const float* node_feats =(const float*)d_in[1];
  const float* W_up       =(const float*)d_in[2];
  const float* W_skip     =(const float*)d_in[3];
  const float* M1         =(const float*)d_in[4];
  const float* M2         =(const float*)d_in[5];
  const float* M3         =(const float*)d_in[6];
  const float* W_out0     =(const float*)d_in[7];
  const float* W_out1     =(const float*)d_in[8];
  const float* W_out2     =(const float*)d_in[9];
  const float* W_down     =(const float*)d_in[10];
  const int*   node_specie=(const int*)d_in[11];
  const int*   senders    =(const int*)d_in[12];
  const int*   receivers  =(const int*)d_in[13];
  float* out=(float*)d_out;
  float* ws=(float*)d_ws;
  float* up  = ws;                       // NN*576 floats
  float* agg = ws + (size_t)NN*576;      // NN*576 floats

  hipMemsetAsync(agg, 0, (size_t)NN*576*sizeof(float), stream);
  node_up_kernel<<<NN/4, 256, 0, stream>>>(node_feats, W_up, up);
  edge_kernel<<<NE/32, 256, 0, stream>>>(vectors, senders, receivers,
                                         M1, M2, M3, up, agg, g_cg);
  final_kernel<<<NN/4, 256, 0, stream>>>(agg, node_feats, node_specie, W_skip,
                                         W_down, W_out0, W_out1, W_out2, out, g_cg);
}

// Round 3
// 1270.649 us; speedup vs baseline: 3.1734x; 3.1734x over previous
//
#include <hip/hip_runtime.h>
#include <complex>
#include <cmath>

// ---------------------------------------------------------------------------
// MarioNette layer (e3nn-style): node linears -> edge tensor-product messages
// with radial MLP weights -> segment sum -> squared tensor products -> output
// linears + soft-norm + skip.  MUL=64, lmax=2, 20000 nodes, 160000 edges.
//
// Internal layout: component-major (i-major) per node/edge so lane=u gathers
// and atomics are 64-lane coalesced 256B segments. Output converted back to
// u-major in the final kernel.
//
// R2 lesson: monolithic final_kernel spilled (VGPR=256, 2.2GB scratch writes,
// 6% VALUBusy). Rewritten with phase-disjoint live sets: dn/sq -> LDS, then
// per-group output linears -> LDS partial, then per-group skip accumulate.
// ---------------------------------------------------------------------------

constexpr int NN = 20000;
constexpr int NE = 160000;

struct CGTab { float v[363]; };
// path order (== PATHS order): (0,0,0)(0,1,1)(0,2,2)(1,0,1)(1,1,0)(1,1,2)
//                              (1,2,1)(2,0,2)(2,1,1)(2,2,0)(2,2,2)
// sizes: 1,9,25,9,9,45,45,25,45,25,125 ; offsets:
// 0,1,10,35,44,53,98,143,168,213,238  (total 363)

// ---------------- host-side CG construction (exact port of reference) ------
static double hfact(int n){ double r=1.0; for(int i=2;i<=n;i++) r*=(double)i; return r; }
static double hcleb(int j1,int m1,int j2,int m2,int j3,int m3){
  if(m1+m2!=m3) return 0.0;
  double pref = std::sqrt((2.0*j3+1.0)*hfact(j3+j1-j2)*hfact(j3-j1+j2)*hfact(j1+j2-j3)/hfact(j1+j2+j3+1));
  pref *= std::sqrt(hfact(j3+m3)*hfact(j3-m3)*hfact(j1-m1)*hfact(j1+m1)*hfact(j2-m2)*hfact(j2+m2));
  double s=0.0;
  for(int k=0;k<=j1+j2-j3;k++){
    int d0=k,d1=j1+j2-j3-k,d2=j1-m1-k,d3=j2+m2-k,d4=j3-j2+m1+k,d5=j3-j1-m2+k;
    if(d0<0||d1<0||d2<0||d3<0||d4<0||d5<0) continue;
    double den=hfact(d0)*hfact(d1)*hfact(d2)*hfact(d3)*hfact(d4)*hfact(d5);
    s += ((k&1)?-1.0:1.0)/den;
  }
  return pref*s;
}
typedef std::complex<double> cdbl;
static void hbuildU(int l, cdbl U[5][5]){
  for(int a=0;a<5;a++)for(int b=0;b<5;b++) U[a][b]=cdbl(0.0,0.0);
  U[l][l]=cdbl(1.0,0.0);
  const double r2=std::sqrt(2.0);
  for(int m=1;m<=l;m++){
    double sgn=(m&1)?-1.0:1.0;
    U[l+m][l+m]=cdbl(sgn/r2,0.0);
    U[l+m][l-m]=cdbl(1.0/r2,0.0);
    U[l-m][l-m]=cdbl(0.0,1.0/r2);
    U[l-m][l+m]=cdbl(0.0,-sgn/r2);
  }
}
static CGTab build_cg(){
  CGTab T{};
  const int L1[11]={0,0,0,1,1,1,1,2,2,2,2};
  const int L2[11]={0,1,2,0,1,1,2,0,1,2,2};
  const int L3[11]={0,1,2,1,0,2,1,2,1,0,2};
  int off=0;
  for(int p=0;p<11;p++){
    int l1=L1[p],l2=L2[p],l3=L3[p];
    int d1=2*l1+1,d2=2*l2+1,d3=2*l3+1;
    cdbl U1[5][5],U2[5][5],U3[5][5];
    hbuildU(l1,U1); hbuildU(l2,U2); hbuildU(l3,U3);
    double Rr[125],Ri[125]; double nr=0.0,ni=0.0;
    for(int a=0;a<d1;a++)for(int b=0;b<d2;b++)for(int c=0;c<d3;c++){
      cdbl s(0.0,0.0);
      for(int i=0;i<d1;i++)for(int j=0;j<d2;j++){
        int k=(i-l1)+(j-l2)+l3;          // m3 = m1+m2 selection rule
        if(k<0||k>=d3) continue;
        double cc=hcleb(l1,i-l1,l2,j-l2,l3,k-l3);
        if(cc==0.0) continue;
        s += U1[a][i]*U2[b][j]*std::conj(U3[c][k])*cc;
      }
      int idx=(a*d2+b)*d3+c;
      Rr[idx]=s.real(); Ri[idx]=s.imag();
      nr+=s.real()*s.real(); ni+=s.imag()*s.imag();
    }
    bool useR=(nr>=ni);
    double nm=std::sqrt(useR?nr:ni);
    int sz=d1*d2*d3;
    for(int t=0;t<sz;t++) T.v[off+t]=(float)((useR?Rr[t]:Ri[t])/nm);
    off+=sz;
  }
  return T;
}
static const CGTab g_cg = build_cg();

// ---------------- device helpers -------------------------------------------
__device__ __forceinline__ float gelu_f(float x){
  // jax.nn.gelu default (approximate=True, tanh form)
  float t = tanhf(0.7978845608028654f*(x + 0.044715f*x*x*x));
  return 0.5f*x*(1.0f+t);
}

// ---------------- K1: up = nf @ W_up / 8  (stored component-major) ----------
__global__ __launch_bounds__(256) void node_up_kernel(
    const float* __restrict__ nf, const float* __restrict__ Wup,
    float* __restrict__ up)
{
  __shared__ alignas(16) float NF[4][576];
  const int tid=threadIdx.x, wid=tid>>6, lane=tid&63;
  const int node=blockIdx.x*4+wid;
  float* F=NF[wid];
  const float* nr=nf+(size_t)node*576;
  #pragma unroll
  for(int t=0;t<9;t++) F[lane+t*64]=nr[lane+t*64];
  __syncthreads();
  float* ur=up+(size_t)node*576;
  { // l=0
    float a=0.f;
    for(int u4=0;u4<16;u4++){
      const float* wb=Wup+(u4*4)*64+lane;
      float w0=wb[0],w1=wb[64],w2=wb[128],w3=wb[192];
      const float4 v=*(const float4*)&F[u4*4];
      a+=v.x*w0+v.y*w1+v.z*w2+v.w*w3;
    }
    ur[lane]=a*0.125f;
  }
  { // l=1 : input u-major F[64+u*3+i]
    float a0=0.f,a1=0.f,a2=0.f;
    for(int u4=0;u4<16;u4++){
      const float* wb=Wup+4096+(u4*4)*64+lane;
      float w0=wb[0],w1=wb[64],w2=wb[128],w3=wb[192];
      const float4 A0=*(const float4*)&F[64+u4*12];
      const float4 A1=*(const float4*)&F[64+u4*12+4];
      const float4 A2=*(const float4*)&F[64+u4*12+8];
      a0 += A0.x*w0 + A0.w*w1 + A1.z*w2 + A2.y*w3;
      a1 += A0.y*w0 + A1.x*w1 + A1.w*w2 + A2.z*w3;
      a2 += A0.z*w0 + A1.y*w1 + A2.x*w2 + A2.w*w3;
    }
    ur[64+lane]=a0*0.125f; ur[128+lane]=a1*0.125f; ur[192+lane]=a2*0.125f;
  }
  { // l=2 : input u-major F[256+u*5+i]
    float a0=0.f,a1=0.f,a2=0.f,a3=0.f,a4=0.f;
    for(int u4=0;u4<16;u4++){
      const float* wb=Wup+8192+(u4*4)*64+lane;
      float w0=wb[0],w1=wb[64],w2=wb[128],w3=wb[192];
      const float4 B0=*(const float4*)&F[256+u4*20];
      const float4 B1=*(const float4*)&F[256+u4*20+4];
      const float4 B2=*(const float4*)&F[256+u4*20+8];
      const float4 B3=*(const float4*)&F[256+u4*20+12];
      const float4 B4=*(const float4*)&F[256+u4*20+16];
      a0 += B0.x*w0 + B1.y*w1 + B2.z*w2 + B3.w*w3;
      a1 += B0.y*w0 + B1.z*w1 + B2.w*w2 + B4.x*w3;
      a2 += B0.z*w0 + B1.w*w1 + B3.x*w2 + B4.y*w3;
      a3 += B0.w*w0 + B2.x*w1 + B3.y*w2 + B4.z*w3;
      a4 += B1.x*w0 + B2.y*w1 + B3.z*w2 + B4.w*w3;
    }
    ur[256+lane]=a0*0.125f; ur[320+lane]=a1*0.125f; ur[384+lane]=a2*0.125f;
    ur[448+lane]=a3*0.125f; ur[512+lane]=a4*0.125f;
  }
}

// ---------------- K2: per-edge radial MLP + tensor-product + scatter --------
// 1 wave = 8 edges; block = 4 waves = 32 edges. (unchanged from R2)
__global__ __launch_bounds__(256) void edge_kernel(
    const float* __restrict__ vectors, const int* __restrict__ senders,
    const int* __restrict__ receivers, const float* __restrict__ M1,
    const float* __restrict__ M2, const float* __restrict__ M3,
    const float* __restrict__ up, float* __restrict__ agg, CGTab cg)
{
  __shared__ alignas(16) float RL[4][64];
  __shared__ alignas(16) float HL[4][512];
  __shared__ alignas(16) float HL2[4][512];
  const int tid=threadIdx.x, wid=tid>>6, lane=tid&63;
  const int ebase=(blockIdx.x*4+wid)*8;

  // radial basis: lane handles edge (lane>>3), basis (lane&7)
  {
    int el = ebase + (lane>>3);
    float vx=vectors[3*el], vy=vectors[3*el+1], vz=vectors[3*el+2];
    float xx=sqrtf(vx*vx+vy*vy+vz*vz);
    float safe=(xx==0.0f)?1.0f:xx;
    float x2=xx*xx;
    float env=(xx<1.0f)? expf(2.0f*x2/fminf(x2-1.0f,-1e-6f)) : 0.0f;
    float nb=(float)((lane&7)+1);
    RL[wid][lane] = 1.4142135623730951f*sinf(3.14159265358979f*nb*xx)/safe*env;
  }
  __syncthreads();
  // h1 = gelu(r @ M1 / sqrt(8))
  {
    float m1v[8];
    #pragma unroll
    for(int b=0;b<8;b++) m1v[b]=M1[b*64+lane];
    #pragma unroll
    for(int e=0;e<8;e++){
      const float4 ra=*(const float4*)&RL[wid][e*8];
      const float4 rb=*(const float4*)&RL[wid][e*8+4];
      float acc = ra.x*m1v[0]+ra.y*m1v[1]+ra.z*m1v[2]+ra.w*m1v[3]
                + rb.x*m1v[4]+rb.y*m1v[5]+rb.z*m1v[6]+rb.w*m1v[7];
      HL[wid][e*64+lane]=gelu_f(acc*0.3535533905932738f);
    }
  }
  __syncthreads();
  // h2 = gelu(h1 @ M2 / 8)
  {
    float h2[8]={0,0,0,0,0,0,0,0};
    for(int k4=0;k4<16;k4++){
      const float* mb=M2+(k4*4)*64+lane;
      float m2a=mb[0],m2b=mb[64],m2c=mb[128],m2d=mb[192];
      #pragma unroll
      for(int e=0;e<8;e++){
        const float4 h=*(const float4*)&HL[wid][e*64+k4*4];
        h2[e] += h.x*m2a+h.y*m2b+h.z*m2c+h.w*m2d;
      }
    }
    #pragma unroll
    for(int e=0;e<8;e++) HL2[wid][e*64+lane]=gelu_f(h2[e]*0.125f);
  }
  __syncthreads();
  // w[e][p] = (h2 @ M3)[p*64+lane]   (scale 1/8 applied later)
  float w[8][11];
  #pragma unroll
  for(int e=0;e<8;e++){
    #pragma unroll
    for(int p=0;p<11;p++) w[e][p]=0.0f;
  }
  for(int k4=0;k4<16;k4++){
    float m3v[4][11];
    #pragma unroll
    for(int q=0;q<4;q++){
      #pragma unroll
      for(int p=0;p<11;p++) m3v[q][p]=M3[(size_t)(k4*4+q)*704+p*64+lane];
    }
    #pragma unroll
    for(int e=0;e<8;e++){
      const float4 h=*(const float4*)&HL2[wid][e*64+k4*4];
      #pragma unroll
      for(int p=0;p<11;p++)
        w[e][p] += h.x*m3v[0][p]+h.y*m3v[1][p]+h.z*m3v[2][p]+h.w*m3v[3][p];
    }
  }
  // per-edge tensor product + atomic scatter
  #pragma unroll
  for(int e=0;e<8;e++){
    const int eid=ebase+e;
    float evx=vectors[3*eid], evy=vectors[3*eid+1], evz=vectors[3*eid+2];
    float len=sqrtf(evx*evx+evy*evy+evz*evz);
    float il=1.0f/fmaxf(len,1e-9f);
    float dx=evx*il, dy=evy*il, dz=evz*il;
    float Y1[3]={1.7320508075688772f*dy, 1.7320508075688772f*dz, 1.7320508075688772f*dx};
    float Y2[5]={3.872983346207417f*dx*dy, 3.872983346207417f*dy*dz,
                 1.118033988749895f*(3.0f*dz*dz-1.0f),
                 3.872983346207417f*dx*dz, 1.9364916731037085f*(dx*dx-dy*dy)};
    int snd=senders[eid], rcv=receivers[eid];
    const float* urow=up+(size_t)snd*576;
    float mA=urow[lane];
    float mB[3], mC[5];
    #pragma unroll
    for(int i=0;i<3;i++) mB[i]=urow[64+i*64+lane];
    #pragma unroll
    for(int i=0;i<5;i++) mC[i]=urow[256+i*64+lane];
    const float wsc=(len==0.0f)?0.0f:0.125f;   // mix/8 and zero at len==0
    float we[11];
    #pragma unroll
    for(int p=0;p<11;p++) we[p]=w[e][p]*wsc;
    float o0=0.0f, o1[3]={0,0,0}, o2[5]={0,0,0,0,0};
    // (0,0,0)
    o0 += we[0]*mA*cg.v[0];
    // (0,1,1): diagonal (U unitarity)
    #pragma unroll
    for(int k=0;k<3;k++) o1[k]+= we[1]*mA*Y1[k]*cg.v[1+k*3+k];
    // (0,2,2): diagonal
    #pragma unroll
    for(int k=0;k<5;k++) o2[k]+= we[2]*mA*Y2[k]*cg.v[10+k*5+k];
    // (1,0,1): diagonal
    #pragma unroll
    for(int k=0;k<3;k++) o1[k]+= we[3]*mB[k]*cg.v[35+k*3+k];
    // (1,1,0)
    #pragma unroll
    for(int i=0;i<3;i++){
      float t=we[4]*mB[i];
      #pragma unroll
      for(int j=0;j<3;j++) o0 += t*Y1[j]*cg.v[44+i*3+j];
    }
    // (1,1,2)
    #pragma unroll
    for(int i=0;i<3;i++){
      float t=we[5]*mB[i];
      #pragma unroll
      for(int j=0;j<3;j++){
        float ty=t*Y1[j];
        #pragma unroll
        for(int k=0;k<5;k++) o2[k]+= ty*cg.v[53+(i*3+j)*5+k];
      }
    }
    // (1,2,1)
    #pragma unroll
    for(int i=0;i<3;i++){
      float t=we[6]*mB[i];
      #pragma unroll
      for(int j=0;j<5;j++){
        float ty=t*Y2[j];
        #pragma unroll
        for(int k=0;k<3;k++) o1[k]+= ty*cg.v[98+(i*5+j)*3+k];
      }
    }
    // (2,0,2): diagonal
    #pragma unroll
    for(int k=0;k<5;k++) o2[k]+= we[7]*mC[k]*cg.v[143+k*5+k];
    // (2,1,1)
    #pragma unroll
    for(int i=0;i<5;i++){
      float t=we[8]*mC[i];
      #pragma unroll
      for(int j=0;j<3;j++){
        float ty=t*Y1[j];
        #pragma unroll
        for(int k=0;k<3;k++) o1[k]+= ty*cg.v[168+(i*3+j)*3+k];
      }
    }
    // (2,2,0)
    #pragma unroll
    for(int i=0;i<5;i++){
      float t=we[9]*mC[i];
      #pragma unroll
      for(int j=0;j<5;j++) o0 += t*Y2[j]*cg.v[213+i*5+j];
    }
    // (2,2,2)
    #pragma unroll
    for(int i=0;i<5;i++){
      float t=we[10]*mC[i];
      #pragma unroll
      for(int j=0;j<5;j++){
        float ty=t*Y2[j];
        #pragma unroll
        for(int k=0;k<5;k++) o2[k]+= ty*cg.v[238+(i*5+j)*5+k];
      }
    }
    float* ar=agg+(size_t)rcv*576;
    const float sc=0.3535533905932738f;  // 1/sqrt(AVG_NEIGH)
    atomicAdd(ar+lane, o0*sc);
    #pragma unroll
    for(int i=0;i<3;i++) atomicAdd(ar+64+i*64+lane, o1[i]*sc);
    #pragma unroll
    for(int i=0;i<5;i++) atomicAdd(ar+256+i*64+lane, o2[i]*sc);
  }
}

// ---------------- K3: dn, squares, output linears, soft-norm, skip, merge ---
// Phase-ordered so register live sets stay disjoint (R2 spill fix):
//   A: stage agg/nf to LDS
//   B: dn + squared tensor products -> LDS cat buffers (dn regs die here)
//   C: per-l output linear + soft-norm -> 0.45*o*f into AG (u-major)
//   E: per-l skip linear, accumulate 0.9*sk into AG, coalesced store
__global__ __launch_bounds__(256) void final_kernel(
    const float* __restrict__ agg, const float* __restrict__ nf,
    const int* __restrict__ specie, const float* __restrict__ Wskip,
    const float* __restrict__ Wdown, const float* __restrict__ Wout0,
    const float* __restrict__ Wout1, const float* __restrict__ Wout2,
    float* __restrict__ out, CGTab cg)
{
  __shared__ alignas(16) float AG[4][576];   // agg (comp-major); reused as merge buf (u-major)
  __shared__ alignas(16) float NF[4][576];
  __shared__ alignas(16) float C0[4][256];
  __shared__ alignas(16) float C1[4][576];
  __shared__ alignas(16) float C2[4][1280];
  const int tid=threadIdx.x, wid=tid>>6, lane=tid&63;
  const int node=blockIdx.x*4+wid;
  float* A=AG[wid]; float* F=NF[wid];
  // ---- Phase A: stage ----
  {
    const float* ar=agg+(size_t)node*576;
    const float* nr=nf+(size_t)node*576;
    #pragma unroll
    for(int t=0;t<9;t++){ A[lane+t*64]=ar[lane+t*64]; F[lane+t*64]=nr[lane+t*64]; }
  }
  __syncthreads();

  // ---- Phase B: dn = (agg @ W_down)/8 (gelu on l0), squares -> C ----
  {
    float dn0, dn1[3], dn2[5];
    { // l0
      float a=0.f;
      for(int u4=0;u4<16;u4++){
        const float* wb=Wdown+(u4*4)*64+lane;
        float w0=wb[0],w1=wb[64],w2=wb[128],w3=wb[192];
        const float4 v=*(const float4*)&A[u4*4];
        a+=v.x*w0+v.y*w1+v.z*w2+v.w*w3;
      }
      dn0=gelu_f(a*0.125f);
    }
    { // l1
      float a0=0.f,a1=0.f,a2=0.f;
      for(int u4=0;u4<16;u4++){
        const float* wb=Wdown+4096+(u4*4)*64+lane;
        float w0=wb[0],w1=wb[64],w2=wb[128],w3=wb[192];
        const float4 v0=*(const float4*)&A[64+u4*4];
        const float4 v1=*(const float4*)&A[128+u4*4];
        const float4 v2=*(const float4*)&A[192+u4*4];
        a0+=v0.x*w0+v0.y*w1+v0.z*w2+v0.w*w3;
        a1+=v1.x*w0+v1.y*w1+v1.z*w2+v1.w*w3;
        a2+=v2.x*w0+v2.y*w1+v2.z*w2+v2.w*w3;
      }
      dn1[0]=a0*0.125f; dn1[1]=a1*0.125f; dn1[2]=a2*0.125f;
    }
    { // l2
      float a[5]={0,0,0,0,0};
      for(int u4=0;u4<16;u4++){
        const float* wb=Wdown+8192+(u4*4)*64+lane;
        float w0=wb[0],w1=wb[64],w2=wb[128],w3=wb[192];
        #pragma unroll
        for(int i=0;i<5;i++){
          const float4 v=*(const float4*)&A[256+i*64+u4*4];
          a[i]+=v.x*w0+v.y*w1+v.z*w2+v.w*w3;
        }
      }
      #pragma unroll
      for(int i=0;i<5;i++) dn2[i]=a[i]*0.125f;
    }
    // squares -> C (component-major; write each value as computed)
    float* c0=C0[wid]; float* c1=C1[wid]; float* c2=C2[wid];
    c0[lane]=dn0;
    c0[64+lane]=dn0*dn0*cg.v[0];                       // sq000
    { float s=0.f;                                      // sq110
      #pragma unroll
      for(int i=0;i<3;i++){
        #pragma unroll
        for(int j=0;j<3;j++) s+=dn1[i]*dn1[j]*cg.v[44+i*3+j];
      }
      c0[128+lane]=s;
    }
    { float s=0.f;                                      // sq220
      #pragma unroll
      for(int i=0;i<5;i++){
        #pragma unroll
        for(int j=0;j<5;j++) s+=dn2[i]*dn2[j]*cg.v[213+i*5+j];
      }
      c0[192+lane]=s;
    }
    #pragma unroll
    for(int i=0;i<3;i++){                               // dn1, sq011
      c1[i*192+lane]=dn1[i];
      c1[i*192+64+lane]=dn0*dn1[i]*cg.v[1+i*3+i];
    }
    { float s[3]={0,0,0};                               // sq121
      #pragma unroll
      for(int i=0;i<3;i++){
        #pragma unroll
        for(int j=0;j<5;j++){
          float t=dn1[i]*dn2[j];
          #pragma unroll
          for(int k=0;k<3;k++) s[k]+=t*cg.v[98+(i*5+j)*3+k];
        }
      }
      #pragma unroll
      for(int k=0;k<3;k++) c1[k*192+128+lane]=s[k];
    }
    #pragma unroll
    for(int i=0;i<5;i++){                               // dn2, sq022
      c2[i*256+lane]=dn2[i];
      c2[i*256+64+lane]=dn0*dn2[i]*cg.v[10+i*5+i];
    }
    { float s[5]={0,0,0,0,0};                           // sq112
      #pragma unroll
      for(int i=0;i<3;i++){
        #pragma unroll
        for(int j=0;j<3;j++){
          float t=dn1[i]*dn1[j];
          #pragma unroll
          for(int k=0;k<5;k++) s[k]+=t*cg.v[53+(i*3+j)*5+k];
        }
      }
      #pragma unroll
      for(int k=0;k<5;k++) c2[k*256+128+lane]=s[k];
    }
    { float s[5]={0,0,0,0,0};                           // sq222
      #pragma unroll
      for(int i=0;i<5;i++){
        #pragma unroll
        for(int j=0;j<5;j++){
          float t=dn2[i]*dn2[j];
          #pragma unroll
          for(int k=0;k<5;k++) s[k]+=t*cg.v[238+(i*5+j)*5+k];
        }
      }
      #pragma unroll
      for(int k=0;k<5;k++) c2[k*256+192+lane]=s[k];
    }
  }
  __syncthreads();

  // ---- Phase C: output linears + soft-norm; 0.45*o*f -> AG (u-major) ----
  { // l0: o0 = cat0 @ Wout0 / 16
    float o0=0.f;
    const float* CC=C0[wid];
    for(int u4=0;u4<64;u4++){
      const float* wb=Wout0+(u4*4)*64+lane;
      float w0=wb[0],w1=wb[64],w2=wb[128],w3=wb[192];
      const float4 v=*(const float4*)&CC[u4*4];
      o0+=v.x*w0+v.y*w1+v.z*w2+v.w*w3;
    }
    o0*=0.0625f;
    float n=fabsf(o0)*1e-5f;
    float s=(n>0.0f)?expf(-1.0f/n):0.0f;
    A[lane]=0.45f*o0/(1.0f+n*s);
  }
  { // l1: o1 = cat1 @ Wout1 / sqrt(192)
    float o1[3]={0,0,0};
    const float* CC=C1[wid];
    for(int u4=0;u4<48;u4++){
      const float* wb=Wout1+(u4*4)*64+lane;
      float w0=wb[0],w1=wb[64],w2=wb[128],w3=wb[192];
      #pragma unroll
      for(int i=0;i<3;i++){
        const float4 v=*(const float4*)&CC[i*192+u4*4];
        o1[i]+=v.x*w0+v.y*w1+v.z*w2+v.w*w3;
      }
    }
    #pragma unroll
    for(int i=0;i<3;i++) o1[i]*=0.07216878364870323f;
    float n=sqrtf(o1[0]*o1[0]+o1[1]*o1[1]+o1[2]*o1[2])*1e-5f;
    float s=(n>0.0f)?expf(-1.0f/n):0.0f;
    float f1=0.45f/(1.0f+n*s);
    #pragma unroll
    for(int i=0;i<3;i++) A[64+lane*3+i]=o1[i]*f1;
  }
  { // l2: o2 = cat2 @ Wout2 / 16
    float o2[5]={0,0,0,0,0};
    const float* CC=C2[wid];
    for(int u4=0;u4<64;u4++){
      const float* wb=Wout2+(u4*4)*64+lane;
      float w0=wb[0],w1=wb[64],w2=wb[128],w3=wb[192];
      #pragma unroll
      for(int i=0;i<5;i++){
        const float4 v=*(const float4*)&CC[i*256+u4*4];
        o2[i]+=v.x*w0+v.y*w1+v.z*w2+v.w*w3;
      }
    }
    #pragma unroll
    for(int i=0;i<5;i++) o2[i]*=0.0625f;
    float n=sqrtf(o2[0]*o2[0]+o2[1]*o2[1]+o2[2]*o2[2]+o2[3]*o2[3]+o2[4]*o2[4])*1e-5f;
    float s=(n>0.0f)?expf(-1.0f/n):0.0f;
    float f2=0.45f/(1.0f+n*s);
    #pragma unroll
    for(int i=0;i<5;i++) A[256+lane*5+i]=o2[i]*f2;
  }

  // ---- Phase E: skip = (nf @ W_skip[sp])/8, accumulate 0.9*sk into AG ----
  const int sp=specie[node];
  const float* Ws=Wskip+(size_t)sp*12288;
  { // l0
    float a=0.f;
    for(int u4=0;u4<16;u4++){
      const float* wb=Ws+(u4*4)*64+lane;
      float w0=wb[0],w1=wb[64],w2=wb[128],w3=wb[192];
      const float4 v=*(const float4*)&F[u4*4];
      a+=v.x*w0+v.y*w1+v.z*w2+v.w*w3;
    }
    A[lane]+=0.1125f*a;            // 0.9 * a/8
  }
  { // l1 (F u-major)
    float a0=0.f,a1=0.f,a2=0.f;
    for(int u4=0;u4<16;u4++){
      const float* wb=Ws+4096+(u4*4)*64+lane;
      float w0=wb[0],w1=wb[64],w2=wb[128],w3=wb[192];
      const float4 A0=*(const float4*)&F[64+u4*12];
      const float4 A1=*(const float4*)&F[64+u4*12+4];
      const float4 A2=*(const float4*)&F[64+u4*12+8];
      a0 += A0.x*w0 + A0.w*w1 + A1.z*w2 + A2.y*w3;
      a1 += A0.y*w0 + A1.x*w1 + A1.w*w2 + A2.z*w3;
      a2 += A0.z*w0 + A1.y*w1 + A2.x*w2 + A2.w*w3;
    }
    A[64+lane*3+0]+=0.1125f*a0;
    A[64+lane*3+1]+=0.1125f*a1;
    A[64+lane*3+2]+=0.1125f*a2;
  }
  { // l2 (F u-major)
    float a0=0.f,a1=0.f,a2=0.f,a3=0.f,a4=0.f;
    for(int u4=0;u4<16;u4++){
      const float* wb=Ws+8192+(u4*4)*64+lane;
      float w0=wb[0],w1=wb[64],w2=wb[128],w3=wb[192];
      const float4 B0=*(const float4*)&F[256+u4*20];
      const float4 B1=*(const float4*)&F[256+u4*20+4];
      const float4 B2=*(const float4*)&F[256+u4*20+8];
      const float4 B3=*(const float4*)&F[256+u4*20+12];
      const float4 B4=*(const float4*)&F[256+u4*20+16];
      a0 += B0.x*w0 + B1.y*w1 + B2.z*w2 + B3.w*w3;
      a1 += B0.y*w0 + B1.z*w1 + B2.w*w2 + B4.x*w3;
      a2 += B0.z*w0 + B1.w*w1 + B3.x*w2 + B4.y*w3;
      a3 += B0.w*w0 + B2.x*w1 + B3.y*w2 + B4.z*w3;
      a4 += B1.x*w0 + B2.y*w1 + B3.z*w2 + B4.w*w3;
    }
    A[256+lane*5+0]+=0.1125f*a0;
    A[256+lane*5+1]+=0.1125f*a1;
    A[256+lane*5+2]+=0.1125f*a2;
    A[256+lane*5+3]+=0.1125f*a3;
    A[256+lane*5+4]+=0.1125f*a4;
  }
  __syncthreads();
  // coalesced u-major store
  float* orow=out+(size_t)node*576;
  #pragma unroll
  for(int t=0;t<9;t++) orow[lane+t*64]=A[lane+t*64];
}

// ---------------- launch ----------------------------------------------------
extern "C" void kernel_launch(void* const* d_in, const int* in_sizes, int n_in,
                              void* d_out, int out_size, void* d_ws, size_t ws_size,
                              hipStream_t stream) {
  (void)in_sizes; (void)n_in; (void)out_size; (void)ws_size;
  const float* vectors    =(const float*)d_in[0];
  const float* node_feats =(const float*)d_in[1];
  const float* W_up       =(const float*)d_in[2];
  const float* W_skip     =(const float*)d_in[3];
  const float* M1         =(const float*)d_in[4];
  const float* M2         =(const float*)d_in[5];
  const float* M3         =(const float*)d_in[6];
  const float* W_out0     =(const float*)d_in[7];
  const float* W_out1     =(const float*)d_in[8];
  const float* W_out2     =(const float*)d_in[9];
  const float* W_down     =(const float*)d_in[10];
  const int*   node_specie=(const int*)d_in[11];
  const int*   senders    =(const int*)d_in[12];
  const int*   receivers  =(const int*)d_in[13];
  float* out=(float*)d_out;
  float* ws=(float*)d_ws;
  float* up  = ws;                       // NN*576 floats
  float* agg = ws + (size_t)NN*576;      // NN*576 floats

  hipMemsetAsync(agg, 0, (size_t)NN*576*sizeof(float), stream);
  node_up_kernel<<<NN/4, 256, 0, stream>>>(node_feats, W_up, up);
  edge_kernel<<<NE/32, 256, 0, stream>>>(vectors, senders, receivers,
                                         M1, M2, M3, up, agg, g_cg);
  final_kernel<<<NN/4, 256, 0, stream>>>(agg, node_feats, node_specie, W_skip,
                                         W_down, W_out0, W_out1, W_out2, out, g_cg);
}